// Round 5
// baseline (1457.846 us; speedup 1.0000x reference)
//
#include <hip/hip_runtime.h>
#include <hip/hip_bf16.h>

#define N_VOX 200000
#define KOFF 27
#define PPK 100000
#define NPAIRS (KOFF * PPK)                        // 2,700,000
#define C 64
#define BN_EPS 1e-5f

#define BSHIFT 9                                   // bucket = 512 sorted pair-positions
#define NB ((NPAIRS + (1 << BSHIFT) - 1) >> BSHIFT) // 5274 buckets
#define NCELL (NB * KOFF)                          // (bucket,k) cells
#define MAXP 640                                   // pairs/bucket cap (512 + max run)
#define MAXV 112                                   // voxels/bucket cap (avg ~38)
#define OSTRIDE 67                                 // odd stride: ds_add banks spread

typedef __bf16 bf16x8 __attribute__((ext_vector_type(8)));
typedef __bf16 bf16x4 __attribute__((ext_vector_type(4)));
typedef float f32x4 __attribute__((ext_vector_type(4)));

// ---------------------------------------------------------------------------
// features fp32 -> bf16 (RNE), vectorized.
// ---------------------------------------------------------------------------
__global__ __launch_bounds__(256)
void convert_features(const float* __restrict__ f, __bf16* __restrict__ fb)
{
    const size_t total4 = (size_t)N_VOX * C / 4;
    const size_t i = (size_t)blockIdx.x * blockDim.x + threadIdx.x;
    if (i >= total4) return;
    const float4 v = ((const float4*)f)[i];
    bf16x4 o;
    o.x = (__bf16)v.x; o.y = (__bf16)v.y; o.z = (__bf16)v.z; o.w = (__bf16)v.w;
    ((bf16x4*)fb)[i] = o;
}

// ---------------------------------------------------------------------------
// weight [k][cin][cout] fp32 -> wt [k][cout][cin] bf16 (transposed for B-frags).
// ---------------------------------------------------------------------------
__global__ __launch_bounds__(256)
void convert_weight(const float* __restrict__ w, __bf16* __restrict__ wt)
{
    const int k = blockIdx.x;
    const float* W = w + (size_t)k * C * C;
    __bf16* Wt = wt + (size_t)k * C * C;
    for (int idx = threadIdx.x; idx < C * C; idx += 256) {
        const int ci = idx >> 6, co = idx & 63;
        Wt[co * C + ci] = (__bf16)W[idx];
    }
}

// ---------------------------------------------------------------------------
// Pass 1: per-voxel histogram of out_idx (int atomics).
// ---------------------------------------------------------------------------
__global__ __launch_bounds__(256)
void hist_vox(const int* __restrict__ out_idx, int* __restrict__ cnt)
{
    const int i = blockIdx.x * 256 + threadIdx.x;
    if (i < NPAIRS) atomicAdd(&cnt[out_idx[i]], 1);
}

// ---------------------------------------------------------------------------
// Generic 3-kernel exclusive scan. scan_write optionally also records the
// first voxel of each bucket (atomicMin) — fuses old bucket_starts pass.
// ---------------------------------------------------------------------------
__global__ __launch_bounds__(256)
void scan_block_sums(const int* __restrict__ src, int n, int* __restrict__ bsum)
{
    __shared__ int s[256];
    const int t = threadIdx.x;
    const int i0 = blockIdx.x * 1024 + t * 4;
    int v = 0;
#pragma unroll
    for (int j = 0; j < 4; ++j) { const int i = i0 + j; if (i < n) v += src[i]; }
    s[t] = v;
    __syncthreads();
    for (int d = 128; d > 0; d >>= 1) {
        if (t < d) s[t] += s[t + d];
        __syncthreads();
    }
    if (t == 0) bsum[blockIdx.x] = s[0];
}

__global__ __launch_bounds__(256)
void scan_base(const int* __restrict__ bsum, int* __restrict__ bbase, int nblk)
{
    __shared__ int s[256];
    const int t = threadIdx.x;
    const int v = (t < nblk) ? bsum[t] : 0;
    s[t] = v;
    for (int d = 1; d < 256; d <<= 1) {
        __syncthreads();
        const int x = (t >= d) ? s[t - d] : 0;
        __syncthreads();
        s[t] += x;
    }
    if (t < nblk) bbase[t] = s[t] - v;
}

__global__ __launch_bounds__(256)
void scan_write(const int* __restrict__ src, int n, const int* __restrict__ bbase,
                int* __restrict__ offs, int* __restrict__ cursor,
                int* __restrict__ bv0)
{
    __shared__ int s[256];
    const int t = threadIdx.x;
    const int i0 = blockIdx.x * 1024 + t * 4;
    int v[4]; int local = 0;
#pragma unroll
    for (int j = 0; j < 4; ++j) {
        const int i = i0 + j;
        v[j] = (i < n) ? src[i] : 0;
        local += v[j];
    }
    s[t] = local;
    for (int d = 1; d < 256; d <<= 1) {
        __syncthreads();
        const int x = (t >= d) ? s[t - d] : 0;
        __syncthreads();
        s[t] += x;
    }
    int run = s[t] - local + bbase[blockIdx.x];
#pragma unroll
    for (int j = 0; j < 4; ++j) {
        const int i = i0 + j;
        if (i < n) {
            offs[i] = run;
            if (cursor) cursor[i] = run;
            if (bv0) atomicMin(&bv0[run >> BSHIFT], i);
            run += v[j];
        }
    }
}

// ---------------------------------------------------------------------------
// Pass 3: histogram over (bucket,k) cells.
// ---------------------------------------------------------------------------
__global__ __launch_bounds__(256)
void cell_hist(const int* __restrict__ out_idx, const int* __restrict__ offs,
               int* __restrict__ cellCnt)
{
    const int i = blockIdx.x * 256 + threadIdx.x;
    if (i >= NPAIRS) return;
    const int v = out_idx[i];
    const int b = offs[v] >> BSHIFT;
    const int k = i / PPK;
    atomicAdd(&cellCnt[b * KOFF + k], 1);
}

// ---------------------------------------------------------------------------
// Pass 4: scatter pair metadata into (bucket,k)-sorted order (metadata only).
// ---------------------------------------------------------------------------
__global__ __launch_bounds__(256)
void scatter_pairs(const int* __restrict__ in_idx, const int* __restrict__ out_idx,
                   const int* __restrict__ offs, const int* __restrict__ bucket_v0,
                   int* __restrict__ cursor, int* __restrict__ sorted_in,
                   unsigned char* __restrict__ sorted_vl)
{
    const int i = blockIdx.x * 256 + threadIdx.x;
    if (i >= NPAIRS) return;
    const int v = out_idx[i];
    const int b = offs[v] >> BSHIFT;
    const int k = i / PPK;
    const int pos = atomicAdd(&cursor[b * KOFF + k], 1);
    sorted_in[pos] = in_idx[i];
    const int vl = v - bucket_v0[b];
    sorted_vl[pos] = (unsigned char)((vl < 255) ? vl : 255);
}

// ---------------------------------------------------------------------------
// Owner-computes bucket GEMM, v5 (de-serialized):
//  - ds_add_f32 guaranteed via unsafeAtomicAdd on the LDS tile (round-4 used
//    plain atomicAdd -> suspected CAS loop = the 910us stall)
//  - metadata (sorted_in / sorted_vl) read from global (L2-hot), not LDS:
//    keeps lgkmcnt free of the ds_add backlog
//  - 2-stage software pipeline: task ti+1's A-frags+vl prefetched during
//    task ti's MFMA + ds_add
// ---------------------------------------------------------------------------
__global__ __launch_bounds__(256)
void gemm_bucket(const __bf16* __restrict__ featb, const __bf16* __restrict__ wtb,
                 const int* __restrict__ cellOffs, const int* __restrict__ bucket_v0,
                 const int* __restrict__ sorted_in, const unsigned char* __restrict__ sorted_vl,
                 float* __restrict__ out, float* __restrict__ stats)
{
    __shared__ float outT[MAXV * OSTRIDE];   // 30.0 KB fp32 accumulation tile
    __shared__ int   s_task[72];
    __shared__ int   s_ntask;
    __shared__ int   s_coff[KOFF + 1];
    __shared__ float s_red[512];

    const int b = blockIdx.x;
    const int t = threadIdx.x;
    const int lane = t & 63, wave = t >> 6;
    const int m16 = lane & 15, quad = lane >> 4;

    if (t < KOFF) s_coff[t] = cellOffs[b * KOFF + t];
    if (t == KOFF) s_coff[KOFF] = (b + 1 < NB) ? cellOffs[(b + 1) * KOFF] : NPAIRS;
    for (int i = t; i < MAXV * OSTRIDE; i += 256) outT[i] = 0.f;
    __syncthreads();

    const int p0 = s_coff[0];
    const int np = min(s_coff[KOFF] - p0, MAXP);
    const int v0 = bucket_v0[b];
    int v1 = (b + 1 < NB) ? bucket_v0[b + 1] : N_VOX;
    int nv = min(v1, N_VOX) - v0;
    nv = max(min(nv, MAXV), 0);

    if (t == 0) {
        int ntk = 0, prev = 0;
        for (int kk = 0; kk < KOFF; ++kk) {
            int e = min(s_coff[kk + 1] - p0, np);
            for (int r = min(prev, np); r < e; r += 16)
                s_task[ntk++] = (kk << 20) | (r << 10) | min(e, r + 16);
            prev = e;
        }
        s_ntask = ntk;
    }
    __syncthreads();

    const int ntask = s_ntask;
    const int t0 = (ntask * wave) >> 2;      // contiguous -> consecutive tasks
    const int t1 = (ntask * (wave + 1)) >> 2; // share k -> B stays in VGPRs
    const int* __restrict__ sin_p = sorted_in + p0;
    const unsigned char* __restrict__ svl_p = sorted_vl + p0;

    int kcur = -1;
    bf16x8 bf[4][2];

    // ---- software pipeline: prefetch stage ----
    bf16x8 A0n = {}, A1n = {};
    int vrn[4] = {255, 255, 255, 255};
    int task_n = 0;
    if (t0 < t1) {
        task_n = s_task[t0];
        const int r0 = (task_n >> 10) & 1023, rend = task_n & 1023;
        const int row = r0 + m16;
        if (row < rend) {
            const __bf16* fp = featb + (size_t)sin_p[row] * C + quad * 8;
            A0n = *(const bf16x8*)fp;
            A1n = *(const bf16x8*)(fp + 32);
        }
#pragma unroll
        for (int reg = 0; reg < 4; ++reg) {
            const int r = r0 + quad * 4 + reg;
            vrn[reg] = (r < rend) ? (int)svl_p[r] : 255;
        }
    }

    for (int ti = t0; ti < t1; ++ti) {
        const int task = task_n;
        const bf16x8 A0 = A0n, A1 = A1n;
        int vr[4];
#pragma unroll
        for (int reg = 0; reg < 4; ++reg) vr[reg] = vrn[reg];

        // issue next task's loads before consuming this one
        if (ti + 1 < t1) {
            task_n = s_task[ti + 1];
            const int r0n = (task_n >> 10) & 1023, rendn = task_n & 1023;
            const int rown = r0n + m16;
            if (rown < rendn) {
                const __bf16* fp = featb + (size_t)sin_p[rown] * C + quad * 8;
                A0n = *(const bf16x8*)fp;
                A1n = *(const bf16x8*)(fp + 32);
            } else {
                A0n = (bf16x8){}; A1n = (bf16x8){};
            }
#pragma unroll
            for (int reg = 0; reg < 4; ++reg) {
                const int r = r0n + quad * 4 + reg;
                vrn[reg] = (r < rendn) ? (int)svl_p[r] : 255;
            }
        }

        const int k = task >> 20;
        if (k != kcur) {                      // wave-uniform
            const __bf16* W = wtb + (size_t)k * C * C;
#pragma unroll
            for (int nt = 0; nt < 4; ++nt) {
                bf[nt][0] = *(const bf16x8*)(W + (nt * 16 + m16) * C + quad * 8);
                bf[nt][1] = *(const bf16x8*)(W + (nt * 16 + m16) * C + 32 + quad * 8);
            }
            kcur = k;
        }

        f32x4 acc[4] = {};
#pragma unroll
        for (int nt = 0; nt < 4; ++nt) {
            acc[nt] = __builtin_amdgcn_mfma_f32_16x16x32_bf16(A0, bf[nt][0], acc[nt], 0, 0, 0);
            acc[nt] = __builtin_amdgcn_mfma_f32_16x16x32_bf16(A1, bf[nt][1], acc[nt], 0, 0, 0);
        }
        // C/D map: col=lane&15 (cout), row=quad*4+reg; native ds_add_f32
#pragma unroll
        for (int nt = 0; nt < 4; ++nt)
#pragma unroll
            for (int reg = 0; reg < 4; ++reg)
                if (vr[reg] < MAXV)
                    unsafeAtomicAdd(&outT[vr[reg] * OSTRIDE + nt * 16 + m16], acc[nt][reg]);
    }
    __syncthreads();

    // owned rows: plain coalesced stores + fused BN stats (c == t&63)
    float s = 0.f, q = 0.f;
    for (int i = t; i < nv * C; i += 256) {
        const int r = i >> 6, c = i & 63;
        const float val = outT[r * OSTRIDE + c];
        out[(size_t)(v0 + r) * C + c] = val;
        s += val; q += val * val;
    }
    s_red[t] = s; s_red[256 + t] = q;
    __syncthreads();
    if (t < 64) {
        s = s_red[t] + s_red[64 + t] + s_red[128 + t] + s_red[192 + t];
        q = s_red[256 + t] + s_red[320 + t] + s_red[384 + t] + s_red[448 + t];
        unsafeAtomicAdd(&stats[t], s);
        unsafeAtomicAdd(&stats[64 + t], q);
    }
}

// ---------------------------------------------------------------------------
// Fallback (round-2, measured 550us): MFMA conv + fp32 atomic scatter.
// ---------------------------------------------------------------------------
__global__ __launch_bounds__(256)
void conv_mfma_atomic(const __bf16* __restrict__ featb, const __bf16* __restrict__ wtb,
                      const int* __restrict__ in_idx, const int* __restrict__ out_idx,
                      float* __restrict__ out)
{
    constexpr int TP = 256;
    constexpr int STRIDE = 72;
    __shared__ __bf16 sA[TP * STRIDE];
    __shared__ int s_out[TP];
    const int k = blockIdx.y;
    const int tile_base = blockIdx.x * TP;
    const int t = threadIdx.x;
    const int lane = t & 63;
    const int wave = t >> 6;
    const int m16 = lane & 15;
    const int quad = lane >> 4;
    const __bf16* Wt = wtb + (size_t)k * C * C;
    bf16x8 bfrag[4][2];
#pragma unroll
    for (int nt = 0; nt < 4; ++nt)
#pragma unroll
        for (int kc = 0; kc < 2; ++kc)
            bfrag[nt][kc] = *(const bf16x8*)(Wt + (nt * 16 + m16) * C + kc * 32 + quad * 8);
    {
        const int pair = tile_base + t;
        s_out[t] = (pair < PPK) ? out_idx[(size_t)k * PPK + pair] : 0;
    }
    const int c8 = t & 7;
    const int r0 = t >> 3;
#pragma unroll
    for (int it = 0; it < 8; ++it) {
        const int r = r0 + it * 32;
        const int pair = tile_base + r;
        const int row = (pair < PPK) ? in_idx[(size_t)k * PPK + pair] : 0;
        const float4 v = *(const float4*)(featb + (size_t)row * C + c8 * 8);
        *(float4*)(sA + r * STRIDE + c8 * 8) = v;
    }
    __syncthreads();
    f32x4 acc[4][4] = {};
    const int mbase = wave * 64;
#pragma unroll
    for (int kc = 0; kc < 2; ++kc) {
        bf16x8 afrag[4];
#pragma unroll
        for (int mt = 0; mt < 4; ++mt)
            afrag[mt] = *(const bf16x8*)(sA + (mbase + mt * 16 + m16) * STRIDE + kc * 32 + quad * 8);
#pragma unroll
        for (int nt = 0; nt < 4; ++nt)
#pragma unroll
            for (int mt = 0; mt < 4; ++mt)
                acc[mt][nt] = __builtin_amdgcn_mfma_f32_16x16x32_bf16(
                    afrag[mt], bfrag[nt][kc], acc[mt][nt], 0, 0, 0);
    }
#pragma unroll
    for (int mt = 0; mt < 4; ++mt)
#pragma unroll
        for (int reg = 0; reg < 4; ++reg) {
            const int r = mbase + mt * 16 + quad * 4 + reg;
            const int pair = tile_base + r;
            if (pair < PPK) {
                float* orow = out + (size_t)s_out[r] * C + m16;
#pragma unroll
                for (int nt = 0; nt < 4; ++nt)
                    unsafeAtomicAdd(orow + nt * 16, acc[mt][nt][reg]);
            }
        }
}

__global__ __launch_bounds__(256)
void stats_kernel(const float* __restrict__ out, float* __restrict__ stats,
                  int rows_per_block)
{
    __shared__ float ssum[256];
    __shared__ float ssq[256];
    const int c = threadIdx.x & 63;
    const int sub = threadIdx.x >> 6;
    const int row0 = blockIdx.x * rows_per_block;
    const int row1 = min(row0 + rows_per_block, N_VOX);
    float s = 0.f, q = 0.f;
    for (int r = row0 + sub; r < row1; r += 4) {
        const float v = out[(size_t)r * C + c];
        s += v; q += v * v;
    }
    ssum[threadIdx.x] = s;
    ssq[threadIdx.x] = q;
    __syncthreads();
    if (sub == 0) {
        s = ssum[c] + ssum[64 + c] + ssum[128 + c] + ssum[192 + c];
        q = ssq[c] + ssq[64 + c] + ssq[128 + c] + ssq[192 + c];
        unsafeAtomicAdd(&stats[c], s);
        unsafeAtomicAdd(&stats[64 + c], q);
    }
}

// ---------------------------------------------------------------------------
// BN finalize + apply (conv bias cancels exactly under BN; never added).
// ---------------------------------------------------------------------------
__global__ void finalize_params(const float* __restrict__ stats,
                                const float* __restrict__ gamma,
                                const float* __restrict__ beta,
                                float* __restrict__ ss)
{
    const int c = threadIdx.x;
    const float inv_n = 1.0f / (float)N_VOX;
    const float mean = stats[c] * inv_n;
    const float var = stats[64 + c] * inv_n - mean * mean;
    const float scale = rsqrtf(var + BN_EPS) * gamma[c];
    ss[c] = scale;
    ss[64 + c] = beta[c] - mean * scale;
}

__global__ __launch_bounds__(256)
void norm_kernel(float* __restrict__ out, const float* __restrict__ ss)
{
    const size_t total4 = (size_t)N_VOX * C / 4;
    const size_t idx = (size_t)blockIdx.x * blockDim.x + threadIdx.x;
    if (idx >= total4) return;
    const int c4 = (int)(idx & 15);
    float4 v = ((const float4*)out)[idx];
    const float4 sc = ((const float4*)ss)[c4];
    const float4 sh = ((const float4*)(ss + 64))[c4];
    v.x = fmaxf(v.x * sc.x + sh.x, 0.f);
    v.y = fmaxf(v.y * sc.y + sh.y, 0.f);
    v.z = fmaxf(v.z * sc.z + sh.z, 0.f);
    v.w = fmaxf(v.w * sc.w + sh.w, 0.f);
    ((float4*)out)[idx] = v;
}

extern "C" void kernel_launch(void* const* d_in, const int* in_sizes, int n_in,
                              void* d_out, int out_size, void* d_ws, size_t ws_size,
                              hipStream_t stream)
{
    const float* features = (const float*)d_in[0];
    const float* weight   = (const float*)d_in[1];
    // d_in[2] = bias: cancels exactly under BatchNorm — unused.
    const float* gamma    = (const float*)d_in[3];
    const float* beta     = (const float*)d_in[4];
    const int*   in_idx   = (const int*)d_in[5];
    const int*   out_idx  = (const int*)d_in[6];
    float* out = (float*)d_out;

    // ---- workspace layout (256B-aligned) — total ~43.4 MB ----
    char* base = (char*)d_ws;
    size_t cur = 0;
    auto alloc = [&](size_t bytes) -> char* {
        char* p = base + cur;
        cur = (cur + bytes + 255) & ~(size_t)255;
        return p;
    };
    __bf16* featb   = (__bf16*)alloc((size_t)N_VOX * C * 2);     // 25.6 MB
    __bf16* wtb     = (__bf16*)alloc((size_t)KOFF * C * C * 2);  // 221 KB
    float*  stats   = (float*)alloc(128 * 4);
    float*  ss      = (float*)alloc(128 * 4);
    int*    cnt     = (int*)alloc((size_t)N_VOX * 4);            // 800 KB
    int*    offs    = (int*)alloc((size_t)N_VOX * 4);            // 800 KB
    int*    b_v0    = (int*)alloc((size_t)NB * 4);               // 21 KB
    int*    cellCnt = (int*)alloc((size_t)NCELL * 4);            // 570 KB
    int*    cellOff = (int*)alloc((size_t)NCELL * 4);
    int*    cursor2 = (int*)alloc((size_t)NCELL * 4);
    int*    bsum    = (int*)alloc(256 * 4);
    int*    bbase   = (int*)alloc(256 * 4);
    int*    s_in    = (int*)alloc((size_t)NPAIRS * 4);           // 10.8 MB
    unsigned char* s_vl = (unsigned char*)alloc((size_t)NPAIRS); // 2.7 MB
    const bool fast = (ws_size >= cur);

    const size_t total4 = (size_t)N_VOX * C / 4;
    const int nb_elem = (int)((total4 + 255) / 256);
    const int nb_pair = (NPAIRS + 255) / 256;

    hipMemsetAsync(stats, 0, 128 * sizeof(float), stream);
    convert_features<<<nb_elem, 256, 0, stream>>>(features, featb);
    convert_weight<<<KOFF, 256, 0, stream>>>(weight, wtb);

    if (fast) {
        hipMemsetAsync(cnt, 0, (size_t)N_VOX * 4, stream);
        hipMemsetAsync(cellCnt, 0, (size_t)NCELL * 4, stream);
        hipMemsetAsync(b_v0, 0x7F, (size_t)NB * 4, stream);      // "infinity"

        hist_vox<<<nb_pair, 256, 0, stream>>>(out_idx, cnt);

        const int nsA = (N_VOX + 1023) / 1024;                   // 196
        scan_block_sums<<<nsA, 256, 0, stream>>>(cnt, N_VOX, bsum);
        scan_base<<<1, 256, 0, stream>>>(bsum, bbase, nsA);
        scan_write<<<nsA, 256, 0, stream>>>(cnt, N_VOX, bbase, offs,
                                            (int*)nullptr, b_v0);

        cell_hist<<<nb_pair, 256, 0, stream>>>(out_idx, offs, cellCnt);

        const int nsB = (NCELL + 1023) / 1024;                   // 140
        scan_block_sums<<<nsB, 256, 0, stream>>>(cellCnt, NCELL, bsum);
        scan_base<<<1, 256, 0, stream>>>(bsum, bbase, nsB);
        scan_write<<<nsB, 256, 0, stream>>>(cellCnt, NCELL, bbase, cellOff,
                                            cursor2, (int*)nullptr);

        scatter_pairs<<<nb_pair, 256, 0, stream>>>(in_idx, out_idx, offs, b_v0,
                                                   cursor2, s_in, s_vl);

        gemm_bucket<<<NB, 256, 0, stream>>>(featb, wtb, cellOff, b_v0,
                                            s_in, s_vl, out, stats);
    } else {
        hipMemsetAsync(out, 0, (size_t)N_VOX * C * sizeof(float), stream);
        dim3 cgrid((PPK + 255) / 256, KOFF);
        conv_mfma_atomic<<<cgrid, 256, 0, stream>>>(featb, wtb, in_idx, out_idx, out);
        const int rpb = (N_VOX + 511) / 512;
        stats_kernel<<<512, 256, 0, stream>>>(out, stats, rpb);
    }

    finalize_params<<<1, 64, 0, stream>>>(stats, gamma, beta, ss);
    norm_kernel<<<nb_elem, 256, 0, stream>>>(out, ss);
}

// Round 6
// 1048.095 us; speedup vs baseline: 1.3909x; 1.3909x over previous
//
#include <hip/hip_runtime.h>
#include <hip/hip_bf16.h>

#define N_VOX 200000
#define KOFF 27
#define PPK 100000
#define NPAIRS (KOFF * PPK)        // 2,700,000
#define C 64
#define BN_EPS 1e-5f
#define CAP 2                      // direct slots per (voxel,k) cell; tail spills
#define SPILL_CAP (1 << 19)        // 512K pairs (expected ~88K; input is fixed seed)
#define STAT_BLOCKS 512

typedef __bf16 bf16x8 __attribute__((ext_vector_type(8)));
typedef __bf16 bf16x4 __attribute__((ext_vector_type(4)));
typedef float f32x4 __attribute__((ext_vector_type(4)));

// ---------------------------------------------------------------------------
// features fp32 -> bf16 (RNE), vectorized.
// ---------------------------------------------------------------------------
__global__ __launch_bounds__(256)
void convert_features(const float* __restrict__ f, __bf16* __restrict__ fb)
{
    const size_t total4 = (size_t)N_VOX * C / 4;
    const size_t i = (size_t)blockIdx.x * blockDim.x + threadIdx.x;
    if (i >= total4) return;
    const float4 v = ((const float4*)f)[i];
    bf16x4 o;
    o.x = (__bf16)v.x; o.y = (__bf16)v.y; o.z = (__bf16)v.z; o.w = (__bf16)v.w;
    ((bf16x4*)fb)[i] = o;
}

// ---------------------------------------------------------------------------
// weight [k][cin][cout] fp32 -> wt [k][cout][cin] bf16 (transposed for B-frags).
// ---------------------------------------------------------------------------
__global__ __launch_bounds__(256)
void convert_weight(const float* __restrict__ w, __bf16* __restrict__ wt)
{
    const int k = blockIdx.x;
    const float* W = w + (size_t)k * C * C;
    __bf16* Wt = wt + (size_t)k * C * C;
    for (int idx = threadIdx.x; idx < C * C; idx += 256) {
        const int ci = idx >> 6, co = idx & 63;
        Wt[co * C + ci] = (__bf16)W[idx];
    }
}

// ---------------------------------------------------------------------------
// Build the direct-addressed rulebook: for each pair, key=(v*27+k);
// j = cnt2[key]++ (low contention: mean 0.5 per cell); first CAP in-indices
// stored at slot[key*CAP+j], the Poisson tail goes to a spill list.
// ---------------------------------------------------------------------------
__global__ __launch_bounds__(256)
void scatter_slots(const int* __restrict__ in_idx, const int* __restrict__ out_idx,
                   int* __restrict__ cnt2, int* __restrict__ slot,
                   int* __restrict__ spill_n, int2* __restrict__ spill)
{
    const int i = blockIdx.x * 256 + threadIdx.x;
    if (i >= NPAIRS) return;
    const int v = out_idx[i];
    const int k = i / PPK;                 // magic-mul div by constant
    const int key = v * KOFF + k;
    const int j = atomicAdd(&cnt2[key], 1);
    const int in = in_idx[i];
    if (j < CAP) {
        slot[key * CAP + j] = in;
    } else {
        const int p = atomicAdd(spill_n, 1);
        if (p < SPILL_CAP) spill[p] = make_int2(in, key);
    }
}

// ---------------------------------------------------------------------------
// Owner-computes GEMM, register accumulation. Wave owns 16 consecutive output
// voxels; loops k=0..26 accumulating the 16x64 C-tile in VGPRs:
//   A[16][64] rows = gathered featb rows of slot j of (voxel,k)  (masked if
//   cell has < j+1 pairs), B = Wt[k], 8*D MFMAs per k (D = wave-max depth).
// No LDS, no scatter: each out row written exactly once with plain stores.
// Metadata (cnt2/slot) for k+1 prefetched during k's MFMA work.
// ---------------------------------------------------------------------------
__global__ __launch_bounds__(256)
void gemm_owner(const __bf16* __restrict__ featb, const __bf16* __restrict__ wtb,
                const int* __restrict__ cnt2, const int* __restrict__ slot,
                float* __restrict__ out)
{
    const int t = threadIdx.x;
    const int lane = t & 63, wave = t >> 6;
    const int m16 = lane & 15, quad = lane >> 4;
    const int vbase = blockIdx.x * 64 + wave * 16;   // 3125 blocks x 4 waves
    const int myv = vbase + m16;

    f32x4 acc[4] = {};

    // prefetch k=0 metadata
    int key = myv * KOFF;
    int c_n = min(cnt2[key], CAP);
    int2 sl_n = ((const int2*)slot)[key];

    for (int k = 0; k < KOFF; ++k) {
        const int cc = c_n;
        const int2 s = sl_n;
        if (k + 1 < KOFF) {                 // issue next k's metadata loads now
            c_n = min(cnt2[key + 1], CAP);
            sl_n = ((const int2*)slot)[key + 1];
        }
        ++key;

        // wave-uniform depth: max over the 16-lane group (same for all quads)
        int D = cc;
        D = max(D, __shfl_xor(D, 1, 16));
        D = max(D, __shfl_xor(D, 2, 16));
        D = max(D, __shfl_xor(D, 4, 16));
        D = max(D, __shfl_xor(D, 8, 16));
        if (D == 0) continue;               // wave-uniform (P ~ 3e-4)

        // B fragments for this k (L2-hot 8.2KB): n=lane&15, kdim=quad*8+j
        const __bf16* W = wtb + (size_t)k * C * C;
        bf16x8 bf[4][2];
#pragma unroll
        for (int nt = 0; nt < 4; ++nt) {
            bf[nt][0] = *(const bf16x8*)(W + (nt * 16 + m16) * C + quad * 8);
            bf[nt][1] = *(const bf16x8*)(W + (nt * 16 + m16) * C + 32 + quad * 8);
        }

        for (int j = 0; j < D; ++j) {       // D <= CAP = 2
            const int fi = (j == 0) ? s.x : s.y;
            bf16x8 a0 = {}, a1 = {};
            if (j < cc) {                   // masked lanes contribute zero rows
                const __bf16* fp = featb + (size_t)fi * C + quad * 8;
                a0 = *(const bf16x8*)fp;
                a1 = *(const bf16x8*)(fp + 32);
            }
#pragma unroll
            for (int nt = 0; nt < 4; ++nt) {
                acc[nt] = __builtin_amdgcn_mfma_f32_16x16x32_bf16(a0, bf[nt][0], acc[nt], 0, 0, 0);
                acc[nt] = __builtin_amdgcn_mfma_f32_16x16x32_bf16(a1, bf[nt][1], acc[nt], 0, 0, 0);
            }
        }
    }

    // C/D map: col = lane&15 (cout within 16-tile), row = quad*4+reg (voxel)
#pragma unroll
    for (int nt = 0; nt < 4; ++nt)
#pragma unroll
        for (int reg = 0; reg < 4; ++reg) {
            const int vm = vbase + quad * 4 + reg;
            out[(size_t)vm * C + nt * 16 + m16] = acc[nt][reg];
        }
}

// ---------------------------------------------------------------------------
// Spill fixup: the few (v,k) cells with >CAP pairs. Wave per pair, lane=cout,
// fp32 dot over bf16 inputs (same numerics as MFMA: bf16 in, fp32 accum),
// one fp32 atomic per lane. Expected ~88K pairs -> ~5.6M atomics (~18us).
// Grid-stride: count read from device memory.
// ---------------------------------------------------------------------------
__global__ __launch_bounds__(256)
void spill_fix(const __bf16* __restrict__ featb, const __bf16* __restrict__ wtb,
               const int2* __restrict__ spill, const int* __restrict__ spill_n,
               float* __restrict__ out)
{
    const int lane = threadIdx.x & 63, wave = threadIdx.x >> 6;
    const int n = min(*spill_n, SPILL_CAP);
    for (int p = blockIdx.x * 4 + wave; p < n; p += gridDim.x * 4) {
        const int2 e = spill[p];
        const int key = e.y;
        const int v = key / KOFF;
        const int k = key - v * KOFF;
        const __bf16* fr = featb + (size_t)e.x * C;          // wave-uniform row
        const __bf16* wr = wtb + (size_t)k * C * C + lane * C; // Wt[k][cout=lane][:]
        float a0 = 0.f, a1 = 0.f;
#pragma unroll
        for (int i = 0; i < C; i += 2) {
            a0 += (float)fr[i] * (float)wr[i];
            a1 += (float)fr[i + 1] * (float)wr[i + 1];
        }
        unsafeAtomicAdd(&out[(size_t)v * C + lane], a0 + a1);
    }
}

// ---------------------------------------------------------------------------
// BN stats, two-stage (no same-address atomic contention):
// stage 1: per-block partial sum/sumsq -> bst[block*128 + {c, 64+c}]
// ---------------------------------------------------------------------------
__global__ __launch_bounds__(256)
void stats_partial(const float* __restrict__ out, float* __restrict__ bst,
                   int rows_per_block)
{
    __shared__ float ssum[256];
    __shared__ float ssq[256];
    const int c = threadIdx.x & 63;
    const int sub = threadIdx.x >> 6;
    const int row0 = blockIdx.x * rows_per_block;
    const int row1 = min(row0 + rows_per_block, N_VOX);
    float s = 0.f, q = 0.f;
    for (int r = row0 + sub; r < row1; r += 4) {
        const float v = out[(size_t)r * C + c];
        s += v; q += v * v;
    }
    ssum[threadIdx.x] = s;
    ssq[threadIdx.x] = q;
    __syncthreads();
    if (sub == 0) {
        s = ssum[c] + ssum[64 + c] + ssum[128 + c] + ssum[192 + c];
        q = ssq[c] + ssq[64 + c] + ssq[128 + c] + ssq[192 + c];
        bst[blockIdx.x * 128 + c] = s;
        bst[blockIdx.x * 128 + 64 + c] = q;
    }
}

// ---------------------------------------------------------------------------
// stage 2 + fold BN into per-channel scale/shift (conv bias cancels under BN).
// ---------------------------------------------------------------------------
__global__ void finalize_params(const float* __restrict__ bst,
                                const float* __restrict__ gamma,
                                const float* __restrict__ beta,
                                float* __restrict__ ss)
{
    const int c = threadIdx.x;    // 64 threads
    float s = 0.f, q = 0.f;
    for (int b = 0; b < STAT_BLOCKS; ++b) {
        s += bst[b * 128 + c];
        q += bst[b * 128 + 64 + c];
    }
    const float inv_n = 1.0f / (float)N_VOX;
    const float mean = s * inv_n;
    const float var = q * inv_n - mean * mean;
    const float scale = rsqrtf(var + BN_EPS) * gamma[c];
    ss[c] = scale;
    ss[64 + c] = beta[c] - mean * scale;
}

__global__ __launch_bounds__(256)
void norm_kernel(float* __restrict__ out, const float* __restrict__ ss)
{
    const size_t total4 = (size_t)N_VOX * C / 4;
    const size_t idx = (size_t)blockIdx.x * blockDim.x + threadIdx.x;
    if (idx >= total4) return;
    const int c4 = (int)(idx & 15);
    float4 v = ((const float4*)out)[idx];
    const float4 sc = ((const float4*)ss)[c4];
    const float4 sh = ((const float4*)(ss + 64))[c4];
    v.x = fmaxf(v.x * sc.x + sh.x, 0.f);
    v.y = fmaxf(v.y * sc.y + sh.y, 0.f);
    v.z = fmaxf(v.z * sc.z + sh.z, 0.f);
    v.w = fmaxf(v.w * sc.w + sh.w, 0.f);
    ((float4*)out)[idx] = v;
}

// ---------------------------------------------------------------------------
// Fallback (round-2, measured 550us conv): MFMA conv + fp32 atomic scatter.
// Used only if ws_size can't hold the ~95MB slot layout.
// ---------------------------------------------------------------------------
__global__ __launch_bounds__(256)
void conv_mfma_atomic(const __bf16* __restrict__ featb, const __bf16* __restrict__ wtb,
                      const int* __restrict__ in_idx, const int* __restrict__ out_idx,
                      float* __restrict__ out)
{
    constexpr int TP = 256;
    constexpr int STRIDE = 72;
    __shared__ __bf16 sA[TP * STRIDE];
    __shared__ int s_out[TP];
    const int k = blockIdx.y;
    const int tile_base = blockIdx.x * TP;
    const int t = threadIdx.x;
    const int lane = t & 63;
    const int wave = t >> 6;
    const int m16 = lane & 15;
    const int quad = lane >> 4;
    const __bf16* Wt = wtb + (size_t)k * C * C;
    bf16x8 bfrag[4][2];
#pragma unroll
    for (int nt = 0; nt < 4; ++nt)
#pragma unroll
        for (int kc = 0; kc < 2; ++kc)
            bfrag[nt][kc] = *(const bf16x8*)(Wt + (nt * 16 + m16) * C + kc * 32 + quad * 8);
    {
        const int pair = tile_base + t;
        s_out[t] = (pair < PPK) ? out_idx[(size_t)k * PPK + pair] : 0;
    }
    const int c8 = t & 7;
    const int r0 = t >> 3;
#pragma unroll
    for (int it = 0; it < 8; ++it) {
        const int r = r0 + it * 32;
        const int pair = tile_base + r;
        const int row = (pair < PPK) ? in_idx[(size_t)k * PPK + pair] : 0;
        const float4 v = *(const float4*)(featb + (size_t)row * C + c8 * 8);
        *(float4*)(sA + r * STRIDE + c8 * 8) = v;
    }
    __syncthreads();
    f32x4 acc[4][4] = {};
    const int mbase = wave * 64;
#pragma unroll
    for (int kc = 0; kc < 2; ++kc) {
        bf16x8 afrag[4];
#pragma unroll
        for (int mt = 0; mt < 4; ++mt)
            afrag[mt] = *(const bf16x8*)(sA + (mbase + mt * 16 + m16) * STRIDE + kc * 32 + quad * 8);
#pragma unroll
        for (int nt = 0; nt < 4; ++nt)
#pragma unroll
            for (int mt = 0; mt < 4; ++mt)
                acc[mt][nt] = __builtin_amdgcn_mfma_f32_16x16x32_bf16(
                    afrag[mt], bfrag[nt][kc], acc[mt][nt], 0, 0, 0);
    }
#pragma unroll
    for (int mt = 0; mt < 4; ++mt)
#pragma unroll
        for (int reg = 0; reg < 4; ++reg) {
            const int r = mbase + mt * 16 + quad * 4 + reg;
            const int pair = tile_base + r;
            if (pair < PPK) {
                float* orow = out + (size_t)s_out[r] * C + m16;
#pragma unroll
                for (int nt = 0; nt < 4; ++nt)
                    unsafeAtomicAdd(orow + nt * 16, acc[mt][nt][reg]);
            }
        }
}

extern "C" void kernel_launch(void* const* d_in, const int* in_sizes, int n_in,
                              void* d_out, int out_size, void* d_ws, size_t ws_size,
                              hipStream_t stream)
{
    const float* features = (const float*)d_in[0];
    const float* weight   = (const float*)d_in[1];
    // d_in[2] = bias: cancels exactly under BatchNorm — unused.
    const float* gamma    = (const float*)d_in[3];
    const float* beta     = (const float*)d_in[4];
    const int*   in_idx   = (const int*)d_in[5];
    const int*   out_idx  = (const int*)d_in[6];
    float* out = (float*)d_out;

    // ---- workspace layout (256B-aligned) — ~95 MB ----
    char* base = (char*)d_ws;
    size_t cur = 0;
    auto alloc = [&](size_t bytes) -> char* {
        char* p = base + cur;
        cur = (cur + bytes + 255) & ~(size_t)255;
        return p;
    };
    __bf16* featb   = (__bf16*)alloc((size_t)N_VOX * C * 2);        // 25.6 MB
    __bf16* wtb     = (__bf16*)alloc((size_t)KOFF * C * C * 2);     // 221 KB
    float*  ss      = (float*)alloc(128 * 4);
    float*  bst     = (float*)alloc((size_t)STAT_BLOCKS * 128 * 4); // 256 KB
    int*    cnt2    = (int*)alloc((size_t)N_VOX * KOFF * 4);        // 21.6 MB
    int*    slot    = (int*)alloc((size_t)N_VOX * KOFF * CAP * 4);  // 43.2 MB
    int*    spill_n = (int*)alloc(256);
    int2*   spill   = (int2*)alloc((size_t)SPILL_CAP * 8);          // 4.2 MB
    const bool fast = (ws_size >= cur);

    const size_t total4 = (size_t)N_VOX * C / 4;
    const int nb_elem = (int)((total4 + 255) / 256);
    const int nb_pair = (NPAIRS + 255) / 256;

    convert_features<<<nb_elem, 256, 0, stream>>>(features, featb);
    convert_weight<<<KOFF, 256, 0, stream>>>(weight, wtb);

    if (fast) {
        hipMemsetAsync(cnt2, 0, (size_t)N_VOX * KOFF * 4, stream);
        hipMemsetAsync(spill_n, 0, 4, stream);

        scatter_slots<<<nb_pair, 256, 0, stream>>>(in_idx, out_idx, cnt2, slot,
                                                   spill_n, spill);

        gemm_owner<<<N_VOX / 64, 256, 0, stream>>>(featb, wtb, cnt2, slot, out);

        spill_fix<<<2048, 256, 0, stream>>>(featb, wtb, spill, spill_n, out);
    } else {
        hipMemsetAsync(out, 0, (size_t)N_VOX * C * sizeof(float), stream);
        dim3 cgrid((PPK + 255) / 256, KOFF);
        conv_mfma_atomic<<<cgrid, 256, 0, stream>>>(featb, wtb, in_idx, out_idx, out);
    }

    const int rpb = (N_VOX + STAT_BLOCKS - 1) / STAT_BLOCKS;
    stats_partial<<<STAT_BLOCKS, 256, 0, stream>>>(out, bst, rpb);
    finalize_params<<<1, 64, 0, stream>>>(bst, gamma, beta, ss);
    norm_kernel<<<nb_elem, 256, 0, stream>>>(out, ss);
}

// Round 7
// 835.731 us; speedup vs baseline: 1.7444x; 1.2541x over previous
//
#include <hip/hip_runtime.h>
#include <hip/hip_bf16.h>

#define N_VOX 200000
#define N_PAD 200192               // 782 blocks * 256 voxels (covers pad)
#define KOFF 27
#define PPK 100000
#define NPAIRS (KOFF * PPK)        // 2,700,000
#define C 64
#define BN_EPS 1e-5f
#define CAP 2
#define SPILL_CAP (1 << 19)
#define STAT_BLOCKS 512
#define WS 68                      // LDS W-tile stride (bf16 elems): 4-way max on b128

typedef __bf16 bf16x8 __attribute__((ext_vector_type(8)));
typedef __bf16 bf16x4 __attribute__((ext_vector_type(4)));
typedef float f32x4 __attribute__((ext_vector_type(4)));

// ---------------------------------------------------------------------------
// features fp32 -> bf16 (RNE), vectorized.
// ---------------------------------------------------------------------------
__global__ __launch_bounds__(256)
void convert_features(const float* __restrict__ f, __bf16* __restrict__ fb)
{
    const size_t total4 = (size_t)N_VOX * C / 4;
    const size_t i = (size_t)blockIdx.x * blockDim.x + threadIdx.x;
    if (i >= total4) return;
    const float4 v = ((const float4*)f)[i];
    bf16x4 o;
    o.x = (__bf16)v.x; o.y = (__bf16)v.y; o.z = (__bf16)v.z; o.w = (__bf16)v.w;
    ((bf16x4*)fb)[i] = o;
}

// ---------------------------------------------------------------------------
// weight [k][cin][cout] fp32 -> wt [k][cout][cin] bf16 (transposed for B-frags).
// ---------------------------------------------------------------------------
__global__ __launch_bounds__(256)
void convert_weight(const float* __restrict__ w, __bf16* __restrict__ wt)
{
    const int k = blockIdx.x;
    const float* W = w + (size_t)k * C * C;
    __bf16* Wt = wt + (size_t)k * C * C;
    for (int idx = threadIdx.x; idx < C * C; idx += 256) {
        const int ci = idx >> 6, co = idx & 63;
        Wt[co * C + ci] = (__bf16)W[idx];
    }
}

// ---------------------------------------------------------------------------
// Build direct-addressed rulebook, K-MAJOR: key = k*N_PAD + v. slot holds up
// to CAP in-indices (sentinel -1 = empty, table memset 0xFF); cnt2 is scratch
// for j-assignment only (gemm never reads it). Tail -> spill list.
// ---------------------------------------------------------------------------
__global__ __launch_bounds__(256)
void scatter_slots(const int* __restrict__ in_idx, const int* __restrict__ out_idx,
                   int* __restrict__ cnt2, int* __restrict__ slot,
                   int* __restrict__ spill_n, int2* __restrict__ spill)
{
    const int i = blockIdx.x * 256 + threadIdx.x;
    if (i >= NPAIRS) return;
    const int v = out_idx[i];
    const int k = i / PPK;
    const int key = k * N_PAD + v;
    const int j = atomicAdd(&cnt2[key], 1);
    const int in = in_idx[i];
    if (j < CAP) {
        slot[key * CAP + j] = in;
    } else {
        const int p = atomicAdd(spill_n, 1);
        if (p < SPILL_CAP) spill[p] = make_int2(in, key);
    }
}

// ---------------------------------------------------------------------------
// Transaction-engineered owner GEMM. Block = 256 voxels, wave = 64 voxels
// (4 x 16-row tiles, acc lives in 64 VGPRs across all 27 k).
//   per k:  W[k] staged LDS once per block (double-buffered, 1 barrier/k)
//           meta: k-major sentinel slots -> fully coalesced int2 loads
//           A: masked per-lane row gathers (quad = 16B chunk -> 4 lanes/line)
// L2 line-transactions/block-k ~= 128(B stage)/block + 4x(8 meta + ~64 A)
// vs round-6's ~220 lines per WAVE-k -> ~5x fewer -> should leave the
// transaction-rate wall.
// ---------------------------------------------------------------------------
__global__ __launch_bounds__(256, 3)
void gemm_k(const __bf16* __restrict__ featb, const __bf16* __restrict__ wtb,
            const int2* __restrict__ slot2, float* __restrict__ out)
{
    __shared__ __bf16 sW[2][64 * WS];   // 17.4 KB double-buffered W tile

    const int t = threadIdx.x;
    const int lane = t & 63, wave = t >> 6;
    const int m16 = lane & 15, quad = lane >> 4;
    const int vwave = blockIdx.x * 256 + wave * 64;

    // staging coords: thread t copies 2x16B of row r
    const int sr = t >> 2;
    const int sc = (t & 3) * 16;

    f32x4 acc[4][4] = {};   // [tile][nt]

    // stage k=0
    {
        const __bf16* W = wtb;
        *(bf16x8*)(&sW[0][sr * WS + sc])     = *(const bf16x8*)(W + sr * C + sc);
        *(bf16x8*)(&sW[0][sr * WS + sc + 8]) = *(const bf16x8*)(W + sr * C + sc + 8);
    }
    __syncthreads();

    for (int k = 0; k < KOFF; ++k) {
        // stage k+1 into the other buffer (overlaps with compute of k)
        if (k + 1 < KOFF) {
            const __bf16* W = wtb + (size_t)(k + 1) * C * C;
            __bf16* dst = &sW[(k + 1) & 1][0];
            *(bf16x8*)(dst + sr * WS + sc)     = *(const bf16x8*)(W + sr * C + sc);
            *(bf16x8*)(dst + sr * WS + sc + 8) = *(const bf16x8*)(W + sr * C + sc + 8);
        }

        // B fragments from LDS (no L2 transactions)
        const __bf16* wb = &sW[k & 1][0];
        bf16x8 bf[4][2];
#pragma unroll
        for (int nt = 0; nt < 4; ++nt) {
            bf[nt][0] = *(const bf16x8*)(wb + (nt * 16 + m16) * WS + quad * 8);
            bf[nt][1] = *(const bf16x8*)(wb + (nt * 16 + m16) * WS + 32 + quad * 8);
        }

        // meta: coalesced int2 slot loads (16 voxels = 128B per tile, quads dup)
        const int2* sl = slot2 + (size_t)k * N_PAD;
        int2 s[4];
#pragma unroll
        for (int tl = 0; tl < 4; ++tl)
            s[tl] = sl[vwave + tl * 16 + m16];

#pragma unroll
        for (int tl = 0; tl < 4; ++tl) {
            bf16x8 a0 = {}, a1 = {};
            if (s[tl].x >= 0) {
                const __bf16* fp = featb + (size_t)s[tl].x * C + quad * 8;
                a0 = *(const bf16x8*)fp;
                a1 = *(const bf16x8*)(fp + 32);
            }
#pragma unroll
            for (int nt = 0; nt < 4; ++nt) {
                acc[tl][nt] = __builtin_amdgcn_mfma_f32_16x16x32_bf16(a0, bf[nt][0], acc[tl][nt], 0, 0, 0);
                acc[tl][nt] = __builtin_amdgcn_mfma_f32_16x16x32_bf16(a1, bf[nt][1], acc[tl][nt], 0, 0, 0);
            }
            if (__ballot(s[tl].y >= 0)) {   // wave-uniform skip of 2nd depth
                bf16x8 b0 = {}, b1 = {};
                if (s[tl].y >= 0) {
                    const __bf16* fp = featb + (size_t)s[tl].y * C + quad * 8;
                    b0 = *(const bf16x8*)fp;
                    b1 = *(const bf16x8*)(fp + 32);
                }
#pragma unroll
                for (int nt = 0; nt < 4; ++nt) {
                    acc[tl][nt] = __builtin_amdgcn_mfma_f32_16x16x32_bf16(b0, bf[nt][0], acc[tl][nt], 0, 0, 0);
                    acc[tl][nt] = __builtin_amdgcn_mfma_f32_16x16x32_bf16(b1, bf[nt][1], acc[tl][nt], 0, 0, 0);
                }
            }
        }
        __syncthreads();   // staged k+1 visible; buf[k&1] free for k+2 staging
    }

    // epilogue: C/D map col=lane&15, row=quad*4+reg; one plain store per value
#pragma unroll
    for (int tl = 0; tl < 4; ++tl)
#pragma unroll
        for (int nt = 0; nt < 4; ++nt)
#pragma unroll
            for (int reg = 0; reg < 4; ++reg) {
                const int v = vwave + tl * 16 + quad * 4 + reg;
                if (v < N_VOX)
                    out[(size_t)v * C + nt * 16 + m16] = acc[tl][nt][reg];
            }
}

// ---------------------------------------------------------------------------
// Spill fixup (cells with >CAP pairs, ~88K expected). Wave per pair, lane=cout.
// ---------------------------------------------------------------------------
__global__ __launch_bounds__(256)
void spill_fix(const __bf16* __restrict__ featb, const __bf16* __restrict__ wtb,
               const int2* __restrict__ spill, const int* __restrict__ spill_n,
               float* __restrict__ out)
{
    const int lane = threadIdx.x & 63, wave = threadIdx.x >> 6;
    const int n = min(*spill_n, SPILL_CAP);
    for (int p = blockIdx.x * 4 + wave; p < n; p += gridDim.x * 4) {
        const int2 e = spill[p];
        const int k = e.y / N_PAD;
        const int v = e.y - k * N_PAD;
        const __bf16* fr = featb + (size_t)e.x * C;
        const __bf16* wr = wtb + (size_t)k * C * C + lane * C;
        float a0 = 0.f, a1 = 0.f;
#pragma unroll
        for (int i = 0; i < C; i += 2) {
            a0 += (float)fr[i] * (float)wr[i];
            a1 += (float)fr[i + 1] * (float)wr[i + 1];
        }
        unsafeAtomicAdd(&out[(size_t)v * C + lane], a0 + a1);
    }
}

// ---------------------------------------------------------------------------
// BN stats stage 1 (after spill fix, so stats are exact).
// ---------------------------------------------------------------------------
__global__ __launch_bounds__(256)
void stats_partial(const float* __restrict__ out, float* __restrict__ bst,
                   int rows_per_block)
{
    __shared__ float ssum[256];
    __shared__ float ssq[256];
    const int c = threadIdx.x & 63;
    const int sub = threadIdx.x >> 6;
    const int row0 = blockIdx.x * rows_per_block;
    const int row1 = min(row0 + rows_per_block, N_VOX);
    float s = 0.f, q = 0.f;
    for (int r = row0 + sub; r < row1; r += 4) {
        const float v = out[(size_t)r * C + c];
        s += v; q += v * v;
    }
    ssum[threadIdx.x] = s;
    ssq[threadIdx.x] = q;
    __syncthreads();
    if (sub == 0) {
        s = ssum[c] + ssum[64 + c] + ssum[128 + c] + ssum[192 + c];
        q = ssq[c] + ssq[64 + c] + ssq[128 + c] + ssq[192 + c];
        bst[blockIdx.x * 128 + c] = s;
        bst[blockIdx.x * 128 + 64 + c] = q;
    }
}

// ---------------------------------------------------------------------------
// Stage 2 (parallelized: 4 chunks of 128 blocks) + fold BN into scale/shift.
// Conv bias cancels exactly under BN — never added.
// ---------------------------------------------------------------------------
__global__ __launch_bounds__(256)
void finalize_params(const float* __restrict__ bst,
                     const float* __restrict__ gamma,
                     const float* __restrict__ beta,
                     float* __restrict__ ss)
{
    __shared__ float red[512];
    const int t = threadIdx.x;
    const int c = t & 63, ch = t >> 6;
    float s = 0.f, q = 0.f;
    for (int b = ch; b < STAT_BLOCKS; b += 4) {
        s += bst[b * 128 + c];
        q += bst[b * 128 + 64 + c];
    }
    red[t] = s; red[256 + t] = q;
    __syncthreads();
    if (t < 64) {
        s = red[c] + red[64 + c] + red[128 + c] + red[192 + c];
        q = red[256 + c] + red[320 + c] + red[384 + c] + red[448 + c];
        const float inv_n = 1.0f / (float)N_VOX;
        const float mean = s * inv_n;
        const float var = q * inv_n - mean * mean;
        const float scale = rsqrtf(var + BN_EPS) * gamma[c];
        ss[c] = scale;
        ss[64 + c] = beta[c] - mean * scale;
    }
}

__global__ __launch_bounds__(256)
void norm_kernel(float* __restrict__ out, const float* __restrict__ ss)
{
    const size_t total4 = (size_t)N_VOX * C / 4;
    const size_t idx = (size_t)blockIdx.x * blockDim.x + threadIdx.x;
    if (idx >= total4) return;
    const int c4 = (int)(idx & 15);
    float4 v = ((const float4*)out)[idx];
    const float4 sc = ((const float4*)ss)[c4];
    const float4 sh = ((const float4*)(ss + 64))[c4];
    v.x = fmaxf(v.x * sc.x + sh.x, 0.f);
    v.y = fmaxf(v.y * sc.y + sh.y, 0.f);
    v.z = fmaxf(v.z * sc.z + sh.z, 0.f);
    v.w = fmaxf(v.w * sc.w + sh.w, 0.f);
    ((float4*)out)[idx] = v;
}

// ---------------------------------------------------------------------------
// Fallback (round-2 structure) — only if ws_size can't hold the slot layout
// (round 6 proved it can; kept for safety).
// ---------------------------------------------------------------------------
__global__ __launch_bounds__(256)
void conv_mfma_atomic(const __bf16* __restrict__ featb, const __bf16* __restrict__ wtb,
                      const int* __restrict__ in_idx, const int* __restrict__ out_idx,
                      float* __restrict__ out)
{
    constexpr int TP = 256;
    constexpr int STRIDE = 72;
    __shared__ __bf16 sA[TP * STRIDE];
    __shared__ int s_out[TP];
    const int k = blockIdx.y;
    const int tile_base = blockIdx.x * TP;
    const int t = threadIdx.x;
    const int lane = t & 63;
    const int wave = t >> 6;
    const int m16 = lane & 15;
    const int quad = lane >> 4;
    const __bf16* Wt = wtb + (size_t)k * C * C;
    bf16x8 bfrag[4][2];
#pragma unroll
    for (int nt = 0; nt < 4; ++nt)
#pragma unroll
        for (int kc = 0; kc < 2; ++kc)
            bfrag[nt][kc] = *(const bf16x8*)(Wt + (nt * 16 + m16) * C + kc * 32 + quad * 8);
    {
        const int pair = tile_base + t;
        s_out[t] = (pair < PPK) ? out_idx[(size_t)k * PPK + pair] : 0;
    }
    const int c8 = t & 7;
    const int r0 = t >> 3;
#pragma unroll
    for (int it = 0; it < 8; ++it) {
        const int r = r0 + it * 32;
        const int pair = tile_base + r;
        const int row = (pair < PPK) ? in_idx[(size_t)k * PPK + pair] : 0;
        const float4 v = *(const float4*)(featb + (size_t)row * C + c8 * 8);
        *(float4*)(sA + r * STRIDE + c8 * 8) = v;
    }
    __syncthreads();
    f32x4 acc[4][4] = {};
    const int mbase = wave * 64;
#pragma unroll
    for (int kc = 0; kc < 2; ++kc) {
        bf16x8 afrag[4];
#pragma unroll
        for (int mt = 0; mt < 4; ++mt)
            afrag[mt] = *(const bf16x8*)(sA + (mbase + mt * 16 + m16) * STRIDE + kc * 32 + quad * 8);
#pragma unroll
        for (int nt = 0; nt < 4; ++nt)
#pragma unroll
            for (int mt = 0; mt < 4; ++mt)
                acc[mt][nt] = __builtin_amdgcn_mfma_f32_16x16x32_bf16(
                    afrag[mt], bfrag[nt][kc], acc[mt][nt], 0, 0, 0);
    }
#pragma unroll
    for (int mt = 0; mt < 4; ++mt)
#pragma unroll
        for (int reg = 0; reg < 4; ++reg) {
            const int r = mbase + mt * 16 + quad * 4 + reg;
            const int pair = tile_base + r;
            if (pair < PPK) {
                float* orow = out + (size_t)s_out[r] * C + m16;
#pragma unroll
                for (int nt = 0; nt < 4; ++nt)
                    unsafeAtomicAdd(orow + nt * 16, acc[mt][nt][reg]);
            }
        }
}

extern "C" void kernel_launch(void* const* d_in, const int* in_sizes, int n_in,
                              void* d_out, int out_size, void* d_ws, size_t ws_size,
                              hipStream_t stream)
{
    const float* features = (const float*)d_in[0];
    const float* weight   = (const float*)d_in[1];
    // d_in[2] = bias: cancels exactly under BatchNorm — unused.
    const float* gamma    = (const float*)d_in[3];
    const float* beta     = (const float*)d_in[4];
    const int*   in_idx   = (const int*)d_in[5];
    const int*   out_idx  = (const int*)d_in[6];
    float* out = (float*)d_out;

    // ---- workspace layout (256B-aligned) — ~95.5 MB ----
    char* base = (char*)d_ws;
    size_t cur = 0;
    auto alloc = [&](size_t bytes) -> char* {
        char* p = base + cur;
        cur = (cur + bytes + 255) & ~(size_t)255;
        return p;
    };
    __bf16* featb   = (__bf16*)alloc((size_t)N_VOX * C * 2);        // 25.6 MB
    __bf16* wtb     = (__bf16*)alloc((size_t)KOFF * C * C * 2);     // 221 KB
    float*  ss      = (float*)alloc(128 * 4);
    float*  bst     = (float*)alloc((size_t)STAT_BLOCKS * 128 * 4); // 256 KB
    int*    cnt2    = (int*)alloc((size_t)KOFF * N_PAD * 4);        // 21.6 MB
    int*    slot    = (int*)alloc((size_t)KOFF * N_PAD * CAP * 4);  // 43.2 MB
    int*    spill_n = (int*)alloc(256);
    int2*   spill   = (int2*)alloc((size_t)SPILL_CAP * 8);          // 4.2 MB
    const bool fast = (ws_size >= cur);

    const size_t total4 = (size_t)N_VOX * C / 4;
    const int nb_elem = (int)((total4 + 255) / 256);
    const int nb_pair = (NPAIRS + 255) / 256;

    convert_features<<<nb_elem, 256, 0, stream>>>(features, featb);
    convert_weight<<<KOFF, 256, 0, stream>>>(weight, wtb);

    if (fast) {
        hipMemsetAsync(cnt2, 0, (size_t)KOFF * N_PAD * 4, stream);
        hipMemsetAsync(slot, 0xFF, (size_t)KOFF * N_PAD * CAP * 4, stream);
        hipMemsetAsync(spill_n, 0, 4, stream);

        scatter_slots<<<nb_pair, 256, 0, stream>>>(in_idx, out_idx, cnt2, slot,
                                                   spill_n, spill);

        gemm_k<<<N_PAD / 256, 256, 0, stream>>>(featb, wtb, (const int2*)slot, out);

        spill_fix<<<2048, 256, 0, stream>>>(featb, wtb, spill, spill_n, out);
    } else {
        hipMemsetAsync(out, 0, (size_t)N_VOX * C * sizeof(float), stream);
        dim3 cgrid((PPK + 255) / 256, KOFF);
        conv_mfma_atomic<<<cgrid, 256, 0, stream>>>(featb, wtb, in_idx, out_idx, out);
    }

    const int rpb = (N_VOX + STAT_BLOCKS - 1) / STAT_BLOCKS;
    stats_partial<<<STAT_BLOCKS, 256, 0, stream>>>(out, bst, rpb);
    finalize_params<<<1, 256, 0, stream>>>(bst, gamma, beta, ss);
    norm_kernel<<<nb_elem, 256, 0, stream>>>(out, ss);
}